// Round 3
// baseline (336.041 us; speedup 1.0000x reference)
//
#include <hip/hip_runtime.h>

typedef float  f32x4 __attribute__((ext_vector_type(4)));
typedef short  s16x8 __attribute__((ext_vector_type(8)));

#define EPS_LN2      0.0017328679513998632f   /* eps*ln2, eps = 0.0025 */
#define INV_EPS_LN2  577.0780163555852f       /* 1/(eps*ln2) */
#define LOG2_36      5.169925001442312f

__device__ __forceinline__ short f2bf(float x) {
  unsigned int u; __builtin_memcpy(&u, &x, 4);
  u = (u + 0x7FFFu + ((u >> 16) & 1u)) >> 16;   // RNE
  return (short)u;
}

#define GLOAD16(g, l) __builtin_amdgcn_global_load_lds( \
    (const __attribute__((address_space(1))) void*)(g), \
    (__attribute__((address_space(3))) void*)(l), 16, 0, 0)

// ---------------------------------------------------------------------------
// k_prep: blocks [0,88) pack W_rt/W_ri into MFMA B-frag order (bf16);
// blocks [88,456) K-split GEMM writing per-job slices pre[23][128][200].
// ---------------------------------------------------------------------------
__global__ __launch_bounds__(256) void k_prep(
    const float* __restrict__ W_rt, const float* __restrict__ W_ri,
    short* __restrict__ frt, short* __restrict__ fri,
    const float* __restrict__ txt, const float* __restrict__ img,
    const float* __restrict__ social,
    const float* __restrict__ W_stat, const float* __restrict__ b_stat,
    const float* __restrict__ W_gt, const float* __restrict__ W_gi,
    float* __restrict__ pre) {
  __shared__ float sA[32][128];
  int bid = blockIdx.x;
  if (bid < 88) {
    int slot = bid * 256 + threadIdx.x;   // 22528 total
    const float* W; short* dst; int f;
    if (slot < 6144) { W = W_rt; dst = frt; f = slot; }
    else             { W = W_ri; dst = fri; f = slot - 6144; }
    int k32 = f >> 8, rem = f & 255, ct = rem >> 6, l = rem & 63;
    int col = ct * 16 + (l & 15);
    int k0  = k32 * 32 + (l >> 4) * 8;
    s16x8 p;
#pragma unroll
    for (int c = 0; c < 8; ++c) {
      float v = (col < 50) ? W[(k0 + c) * 50 + col] : 0.f;
      p[c] = f2bf(v);
    }
    *(s16x8*)(dst + (long)f * 8) = p;
    return;
  }
  int gb = bid - 88;
  int job = gb >> 4, rb = (gb >> 2) & 3, cb = gb & 3;
  int t = threadIdx.x, r0 = rb * 32;
  const float* W; int k0, klen;
  if (job < 6)       { k0 = job * 128;       klen = 128; W = W_gt; }
  else if (job == 6) { k0 = 0;               klen = 100; W = W_gt + 768 * 200; }
  else               { k0 = (job - 7) * 128; klen = 128; W = W_gi; }
  if (job == 6) {
    for (int idx = t; idx < 4096; idx += 256) {
      int r = idx >> 7, k = idx & 127;
      float v = 0.f;
      if (k < 100) {
        v = b_stat[k];
#pragma unroll
        for (int u = 0; u < 10; ++u) v += social[(r0 + r) * 10 + u] * W_stat[u * 100 + k];
        v = fmaxf(v, 0.f);
      }
      sA[r][k] = v;
    }
  } else {
    const float* A = (job < 6) ? txt : img;
    int K_A = (job < 6) ? 768 : 2048;
    for (int idx = t; idx < 4096; idx += 256) {
      int r = idx >> 7, k = idx & 127;
      sA[r][k] = A[(r0 + r) * K_A + k0 + k];
    }
  }
  __syncthreads();
  int c = cb * 64 + (t & 63), rg = t >> 6;
  if (c < 200) {
    float acc[8];
#pragma unroll
    for (int i = 0; i < 8; ++i) acc[i] = 0.f;
    for (int k4 = 0; k4 < klen; k4 += 4) {
      float w0 = W[(k0 + k4    ) * 200 + c];
      float w1 = W[(k0 + k4 + 1) * 200 + c];
      float w2 = W[(k0 + k4 + 2) * 200 + c];
      float w3 = W[(k0 + k4 + 3) * 200 + c];
#pragma unroll
      for (int i = 0; i < 8; ++i) {
        f32x4 a = *(const f32x4*)&sA[rg * 8 + i][k4];
        acc[i] += a[0]*w0 + a[1]*w1 + a[2]*w2 + a[3]*w3;
      }
    }
    float* dst = pre + (long)job * 25600;
#pragma unroll
    for (int i = 0; i < 8; ++i)
      dst[(r0 + rg * 8 + i) * 200 + c] = acc[i];
  }
}

// ---------------------------------------------------------------------------
// Projection GEMM, m97-style: per K-step stage A(8KB)+B(4KB) to double-
// buffered LDS via global_load_lds (no VGPR cost, stays in flight across
// the step), one barrier per step. LDS layout == fragment read order
// (per-lane contiguous 16B -> conflict-free ds_read_b128), achieved by
// permuting the per-lane GLOBAL source (the LDS dest of global_load_lds is
// linear wave-uniform-base + lane*16).
// One block = 64 rows (wave w owns rows w*16..), full K.
// out[M][64] = relu(A[M][K] @ W + bias).
// ---------------------------------------------------------------------------
template<int K32>
__device__ __forceinline__ void proj_body(const float* __restrict__ A,
                                          const short* __restrict__ Bf,
                                          const float* __restrict__ bias,
                                          float* __restrict__ out, int bid,
                                          char* smem) {
  char* abuf = smem;            // [2][8192]
  char* bbuf = smem + 16384;    // [2][4096]
  int wave = threadIdx.x >> 6, lane = threadIdx.x & 63;
  int rl = lane & 15, q = lane >> 4;
  int row0 = bid * 64;
  const int K = K32 * 32;
  const float* arow = A + (long)(row0 + wave * 16 + rl) * K + q * 8;
  const short* brow = Bf + wave * 512 + lane * 8;

#define PROJ_STAGE(KK, PH) { \
    const float* asrc = arow + (KK) * 32; \
    char* ad = abuf + (PH) * 8192 + wave * 2048; \
    GLOAD16(asrc,     ad); \
    GLOAD16(asrc + 4, ad + 1024); \
    GLOAD16(brow + (long)(KK) * 2048, bbuf + (PH) * 4096 + wave * 1024); \
  }

  f32x4 acc[4];
#pragma unroll
  for (int ct = 0; ct < 4; ++ct) acc[ct] = (f32x4){0.f, 0.f, 0.f, 0.f};

  PROJ_STAGE(0, 0);
  __syncthreads();                       // compiler drains vmcnt before barrier

  for (int k = 0; k < K32; ++k) {
    if (k + 1 < K32) PROJ_STAGE(k + 1, (k + 1) & 1);
    const char* ab = abuf + (k & 1) * 8192 + wave * 2048 + lane * 16;
    const char* bb = bbuf + (k & 1) * 4096 + lane * 16;
    f32x4 a0 = *(const f32x4*)(ab);
    f32x4 a1 = *(const f32x4*)(ab + 1024);
    s16x8 af;
    af[0]=f2bf(a0[0]); af[1]=f2bf(a0[1]); af[2]=f2bf(a0[2]); af[3]=f2bf(a0[3]);
    af[4]=f2bf(a1[0]); af[5]=f2bf(a1[1]); af[6]=f2bf(a1[2]); af[7]=f2bf(a1[3]);
#pragma unroll
    for (int ct = 0; ct < 4; ++ct) {
      s16x8 bfr = *(const s16x8*)(bb + ct * 1024);
      acc[ct] = __builtin_amdgcn_mfma_f32_16x16x32_bf16(af, bfr, acc[ct], 0, 0, 0);
    }
    __syncthreads();                     // readers done + next stage landed
  }
#undef PROJ_STAGE

#pragma unroll
  for (int ct = 0; ct < 4; ++ct) {
    int col = ct * 16 + rl;
    float bv = (col < 50) ? bias[col] : 0.f;
#pragma unroll
    for (int r = 0; r < 4; ++r) {
      int grow = row0 + wave * 16 + q * 4 + r;   // D row = quad*4+reg (m89)
      float v = fmaxf(acc[ct][r] + bv, 0.f);
      out[(long)grow * 64 + col] = (col < 50) ? v : 0.f;
    }
  }
}

// MLP tail body: one block per batch row; sums the 23 per-job GEMM slices.
__device__ __forceinline__ void mix_body(
    int r, const float* __restrict__ pre,
    const float* __restrict__ b_gt, const float* __restrict__ b_gi,
    const float* __restrict__ W_m1, const float* __restrict__ b_m1,
    const float* __restrict__ W_m2, const float* __restrict__ b_m2,
    float* __restrict__ mix, float* smem) {
  float* sm = smem;            // [200]
  float* sh = smem + 200;      // [100]
  int t = threadIdx.x;
  if (t < 200) {
    float s1 = b_gt[t], s2 = b_gi[t];
#pragma unroll
    for (int j = 0; j < 7; ++j)  s1 += pre[(long)j * 25600 + r * 200 + t];
#pragma unroll
    for (int j = 7; j < 23; ++j) s2 += pre[(long)j * 25600 + r * 200 + t];
    sm[t] = fmaxf(s1, 0.f) + fmaxf(s2, 0.f);
  }
  __syncthreads();
  if (t < 100) {
    float a = b_m1[t];
#pragma unroll 4
    for (int k = 0; k < 200; ++k) a += sm[k] * W_m1[k * 100 + t];
    sh[t] = fmaxf(a, 0.f);
  }
  __syncthreads();
  if (t < 2) {
    float a = b_m2[t];
    for (int k = 0; k < 100; ++k) a += sh[k] * W_m2[k * 2 + t];
    mix[r * 2 + t] = a;
  }
}

// Grid order: img proj [0,72) first (longest: 64 steps), txt proj [72,584),
// mix [584,712) last (tiny).
__global__ __launch_bounds__(256)
void k_pm(
    const float* __restrict__ txt_region, const short* __restrict__ frt,
    const float* __restrict__ b_rt, float* __restrict__ tr,
    const float* __restrict__ img_region, const short* __restrict__ fri,
    const float* __restrict__ b_ri, float* __restrict__ ir,
    const float* __restrict__ pre,
    const float* __restrict__ b_gt, const float* __restrict__ b_gi,
    const float* __restrict__ W_m1, const float* __restrict__ b_m1,
    const float* __restrict__ W_m2, const float* __restrict__ b_m2,
    float* __restrict__ mix) {
  __shared__ __align__(16) char smem[24576];
  int bid = blockIdx.x;
  if (bid < 72)       proj_body<64>(img_region, fri, b_ri, ir, bid, smem);
  else if (bid < 584) proj_body<24>(txt_region, frt, b_rt, tr, bid - 72, smem);
  else                mix_body(bid - 584, pre, b_gt, b_gi, W_m1, b_m1, W_m2, b_m2, mix, (float*)smem);
}

// ---------------------------------------------------------------------------
// Merged Sinkhorn kernel, MAX-PLUS. role 0: xx (n x n), role 1: xy (n x 36),
// role 2: yy (36 x 36). XX holds its C column-slice in 16 named f32x4 regs,
// pinned with an opaque asm so the compiler cannot re-load from global
// inside the 40-iteration loop (round-2: 56 VGPR + 32MB scratch spill).
// ---------------------------------------------------------------------------
#define SK_SMEM 50736

__global__ __launch_bounds__(1024)
__attribute__((amdgpu_waves_per_eu(4, 4)))
void k_sink(
    const float* __restrict__ tr, const float* __restrict__ ir,
    const int* __restrict__ amask, float* __restrict__ Cxx,
    float* __restrict__ Sxy, float* __restrict__ Sxx, float* __restrict__ Syy) {
  __shared__ __align__(16) char smem[SK_SMEM];
  int role = blockIdx.x >> 7;
  int b    = blockIdx.x & 127;
  int tid  = threadIdx.x;

  if (role == 0) {
    // ====================== XX ======================
    short* Xf    = (short*)smem;                 // 32 KB
    float* norms = (float*)(smem + 32768);       // [256]
    float* sA    = (float*)(smem + 33792);       // [256]
    float* sF    = (float*)(smem + 34816);       // [256]
    float* sG    = (float*)(smem + 35840);       // [256]
    float* sPm   = (float*)(smem + 36864);       // [4][256]
    int*   nsh   = (int*)  (smem + 40960);
    if (tid < 64) {
      int c = 0;
      for (int i = tid; i < 256; i += 64) c += amask[b * 256 + i];
#pragma unroll
      for (int o = 1; o < 64; o <<= 1) c += __shfl_xor(c, o);
      if (tid == 0) *nsh = c;
    }
    const float* Xg = tr + (long)b * 256 * 64;
    for (int slot = tid; slot < 2048; slot += 1024) {
      int t = slot >> 7, k32 = (slot >> 6) & 1, l = slot & 63;
      int row = t * 16 + (l & 15), k0 = k32 * 32 + (l >> 4) * 8;
      const float* src = Xg + row * 64 + k0;
      f32x4 a0 = *(const f32x4*)src, a1 = *(const f32x4*)(src + 4);
      s16x8 p;
      p[0]=f2bf(a0[0]); p[1]=f2bf(a0[1]); p[2]=f2bf(a0[2]); p[3]=f2bf(a0[3]);
      p[4]=f2bf(a1[0]); p[5]=f2bf(a1[1]); p[6]=f2bf(a1[2]); p[7]=f2bf(a1[3]);
      *(s16x8*)(Xf + slot * 8) = p;
    }
    __syncthreads();
    int n = *nsh;
    // G = X X^T via MFMA. wave wv owns 16-row strip.
    int wv = tid >> 6, lane = tid & 63, q = lane >> 4;
    f32x4 acc[16];
#pragma unroll
    for (int ct = 0; ct < 16; ++ct) acc[ct] = (f32x4){0.f, 0.f, 0.f, 0.f};
    s16x8 afr0 = *(const s16x8*)(Xf + ((wv * 2 + 0) * 64 + lane) * 8);
    s16x8 afr1 = *(const s16x8*)(Xf + ((wv * 2 + 1) * 64 + lane) * 8);
#pragma unroll
    for (int ct = 0; ct < 16; ++ct) {
      s16x8 b0 = *(const s16x8*)(Xf + ((ct * 2 + 0) * 64 + lane) * 8);
      s16x8 b1 = *(const s16x8*)(Xf + ((ct * 2 + 1) * 64 + lane) * 8);
      acc[ct] = __builtin_amdgcn_mfma_f32_16x16x32_bf16(afr0, b0, acc[ct], 0, 0, 0);
      acc[ct] = __builtin_amdgcn_mfma_f32_16x16x32_bf16(afr1, b1, acc[ct], 0, 0, 0);
    }
#pragma unroll
    for (int r = 0; r < 4; ++r) {                 // diag of tile (wv,wv) = ||x||^2
      int m_ = q * 4 + r;
      if ((lane & 15) == m_) norms[wv * 16 + m_] = acc[wv][r];
    }
    __syncthreads();
    float* Cwb = Cxx + (long)b * 65536;           // D = -C/(eps ln2), f32, global
    if (wv * 16 < n) {                            // skip row-tiles entirely >= n
#pragma unroll
      for (int ct = 0; ct < 16; ++ct) {
        int gj = ct * 16 + (lane & 15);
        float nj = norms[gj];
#pragma unroll
        for (int r = 0; r < 4; ++r) {
          int gi = wv * 16 + q * 4 + r;
          Cwb[gi * 256 + gj] = (acc[ct][r] - 0.5f * (norms[gi] + nj)) * INV_EPS_LN2;
        }
      }
    }
    __syncthreads();
    // kk wave-uniform so prefix-skipping has no divergence
    int kk = tid >> 8, j = tid & 255, i0 = kk * 64;
    int iend = n - i0; if (iend > 64) iend = 64;
    f32x4 c0, c1, c2, c3, c4, c5, c6, c7, c8, c9, ca, cb, cc, cd, ce, cf;
    if (i0 < n) {                                 // wave-uniform chunk guard
      const float* cp = Cwb + (long)i0 * 256 + j;
#define XXLD(CV, T0) \
      CV[0] = cp[(T0+0)*256]; CV[1] = cp[(T0+1)*256]; \
      CV[2] = cp[(T0+2)*256]; CV[3] = cp[(T0+3)*256];
      XXLD(c0, 0)  XXLD(c1, 4)  XXLD(c2, 8)  XXLD(c3, 12)
      XXLD(c4, 16) XXLD(c5, 20) XXLD(c6, 24) XXLD(c7, 28)
      XXLD(c8, 32) XXLD(c9, 36) XXLD(ca, 40) XXLD(cb, 44)
      XXLD(cc, 48) XXLD(cd, 52) XXLD(ce, 56) XXLD(cf, 60)
#undef XXLD
      // opaque pin: values no longer provably == memory -> no remat/reload
      asm volatile("" : "+v"(c0), "+v"(c1), "+v"(c2), "+v"(c3),
                        "+v"(c4), "+v"(c5), "+v"(c6), "+v"(c7),
                        "+v"(c8), "+v"(c9), "+v"(ca), "+v"(cb),
                        "+v"(cc), "+v"(cd), "+v"(ce), "+v"(cf));
    }
    float log2n = log2f((float)n);
    if (tid < 256) { sF[tid] = 0.f; sA[tid] = (tid < n) ? -log2n : -1e30f; }
    __syncthreads();
    const float* ap2 = sA + i0;
#define XXG(CA, CB, CC, CD, OFF) { \
      f32x4 A0 = *(const f32x4*)(ap2 + OFF); \
      f32x4 A1 = *(const f32x4*)(ap2 + OFF + 4); \
      f32x4 A2 = *(const f32x4*)(ap2 + OFF + 8); \
      f32x4 A3 = *(const f32x4*)(ap2 + OFF + 12); \
      float x0 = A0[0]+CA[0], x1 = A0[1]+CA[1], x2 = A0[2]+CA[2], x3 = A0[3]+CA[3]; \
      float x4 = A1[0]+CB[0], x5 = A1[1]+CB[1], x6 = A1[2]+CB[2], x7 = A1[3]+CB[3]; \
      float x8 = A2[0]+CC[0], x9 = A2[1]+CC[1], xa = A2[2]+CC[2], xb = A2[3]+CC[3]; \
      float xc = A3[0]+CD[0], xd = A3[1]+CD[1], xe = A3[2]+CD[2], xf = A3[3]+CD[3]; \
      float y0 = fmaxf(fmaxf(x0, x1), x2); \
      float y1 = fmaxf(fmaxf(x3, x4), x5); \
      float y2 = fmaxf(fmaxf(x6, x7), x8); \
      float y3 = fmaxf(fmaxf(x9, xa), xb); \
      float y4 = fmaxf(fmaxf(xc, xd), xe); \
      m = fmaxf(m, fmaxf(fmaxf(fmaxf(y0, y1), fmaxf(y2, y3)), fmaxf(y4, xf))); }
    for (int h = 0; h < 40; ++h) {
      float m = -1e30f;
      if (i0 < n && j < n) {
        XXG(c0, c1, c2, c3, 0)
        if (iend > 16) { XXG(c4, c5, c6, c7, 16) }
        if (iend > 32) { XXG(c8, c9, ca, cb, 32) }
        if (iend > 48) { XXG(cc, cd, ce, cf, 48) }
      }
      sPm[kk * 256 + j] = m;
      __syncthreads();
      if (tid < 256) {
        float m4 = fmaxf(fmaxf(sPm[tid], sPm[256 + tid]),
                         fmaxf(sPm[512 + tid], sPm[768 + tid]));
        if (tid < n) {
          ((h & 1) ? sF : sG)[tid] = -EPS_LN2 * m4;
          sA[tid] = -log2n - m4;
        }
      }
      __syncthreads();
    }
#undef XXG
    if (tid < 64) {
      float a = 0.f;
      for (int i = tid; i < n; i += 64) a += sF[i] + sG[i];
#pragma unroll
      for (int o = 1; o < 64; o <<= 1) a += __shfl_xor(a, o);
      if (tid == 0) Sxx[b] = a / n;
    }
  } else if (role == 1) {
    // ====================== XY ======================
    float* Ys  = (float*)smem;                    // [36][64]
    float* Cs  = (float*)(smem + 9216);           // [256][37]
    float* nx  = (float*)(smem + 47104);          // [256]
    float* ny  = (float*)(smem + 48128);          // [36]
    float* sA  = (float*)(smem + 48288);          // padded alpha [272]
    float* sB  = (float*)(smem + 49376);          // beta [36]
    float* sF  = (float*)(smem + 49536);          // [256]
    float* sG  = (float*)(smem + 50560);          // [36]
    int*   nsh = (int*)  (smem + 50720);
    if (tid < 64) {
      int c = 0;
      for (int i = tid; i < 256; i += 64) c += amask[b * 256 + i];
#pragma unroll
      for (int o = 1; o < 64; o <<= 1) c += __shfl_xor(c, o);
      if (tid == 0) *nsh = c;
    }
    const float* Xg = tr + (long)b * 256 * 64;
    const float* Yg = ir + (long)b * 36 * 64;
    for (int idx = tid; idx < 576; idx += 1024) {
      int row = idx >> 4, q4 = idx & 15;
      *(f32x4*)(Ys + row * 64 + q4 * 4) = *(const f32x4*)(Yg + row * 64 + q4 * 4);
    }
    __syncthreads();
    int n = *nsh;
    if (tid < 256) {
      float a = 0.f;
#pragma unroll
      for (int q4 = 0; q4 < 13; ++q4) {
        f32x4 v = *(const f32x4*)(Xg + tid * 64 + q4 * 4);
        a += v[0]*v[0] + v[1]*v[1] + v[2]*v[2] + v[3]*v[3];
      }
      nx[tid] = a;
    } else if (tid < 292) {
      int jj = tid - 256; float a = 0.f;
#pragma unroll
      for (int q4 = 0; q4 < 13; ++q4) {
        f32x4 v = *(const f32x4*)(Ys + jj * 64 + q4 * 4);
        a += v[0]*v[0] + v[1]*v[1] + v[2]*v[2] + v[3]*v[3];
      }
      ny[jj] = a;
    }
    __syncthreads();
    if (tid < 1008) {
      int ii = tid / 36, jj = tid - ii * 36;
      f32x4 yr[13];
#pragma unroll
      for (int q4 = 0; q4 < 13; ++q4) yr[q4] = *(const f32x4*)(Ys + jj * 64 + q4 * 4);
      float nyj = ny[jj];
      for (int i = ii; i < 256; i += 28) {
        float d = 0.f;
#pragma unroll
        for (int q4 = 0; q4 < 13; ++q4) {
          f32x4 xv = *(const f32x4*)(Xg + i * 64 + q4 * 4);
          d += xv[0]*yr[q4][0] + xv[1]*yr[q4][1] + xv[2]*yr[q4][2] + xv[3]*yr[q4][3];
        }
        Cs[i * 37 + jj] = (d - 0.5f * (nx[i] + nyj)) * INV_EPS_LN2;
      }
    }
    __syncthreads();
    int jg = tid >> 4, kg = tid & 15;             // g-role: column jg, slice kg
    float Cg[16];
    if (jg < 36) {
#pragma unroll
      for (int t = 0; t < 16; ++t) Cg[t] = Cs[(kg * 16 + t) * 37 + jg];
    }
    int fi = tid >> 2, kf = tid & 3;              // f-role: row fi, slice kf
    float Cf[9];
#pragma unroll
    for (int t = 0; t < 9; ++t) {
      int jj2 = kf * 9 + t;
      Cf[t] = (jj2 < 36) ? Cs[fi * 37 + jj2] : 0.f;
    }
    float log2n = log2f((float)n);
    if (tid < 256) { sF[tid] = 0.f; sA[tid + (tid >> 4)] = -log2n; }
    __syncthreads();
    const float* agp = sA + kg * 17;
    int gend = n - kg * 16; if (gend > 16) gend = 16;
    for (int it = 0; it < 20; ++it) {
      float gm = -1e30f;
      if (jg < 36) {
#pragma unroll
        for (int t = 0; t < 16; ++t)
          if (t < gend) gm = fmaxf(gm, agp[t] + Cg[t]);
        gm = fmaxf(gm, __shfl_xor(gm, 1)); gm = fmaxf(gm, __shfl_xor(gm, 2));
        gm = fmaxf(gm, __shfl_xor(gm, 4)); gm = fmaxf(gm, __shfl_xor(gm, 8));
      }
      __syncthreads();
      if (jg < 36 && kg == 0) {
        sG[jg] = -EPS_LN2 * gm;
        sB[jg] = -LOG2_36 - gm;
      }
      __syncthreads();
      float fm = -1e30f;
#pragma unroll
      for (int t = 0; t < 9; ++t) {
        int jj2 = kf * 9 + t;
        if (jj2 < 36) fm = fmaxf(fm, sB[jj2] + Cf[t]);
      }
      fm = fmaxf(fm, __shfl_xor(fm, 1)); fm = fmaxf(fm, __shfl_xor(fm, 2));
      __syncthreads();
      if (kf == 0 && fi < n) {
        sF[fi] = -EPS_LN2 * fm;
        sA[fi + (fi >> 4)] = -log2n - fm;
      }
      __syncthreads();
    }
    if (tid < 64) {
      float a = 0.f;
      for (int i = tid; i < n; i += 64) a += sF[i];
      float g = (tid < 36) ? sG[tid] : 0.f;
#pragma unroll
      for (int o = 1; o < 64; o <<= 1) { a += __shfl_xor(a, o); g += __shfl_xor(g, o); }
      if (tid == 0) Sxy[b] = a / n + g / 36.f;
    }
  } else {
    // ====================== YY ======================
    float* Ys = (float*)smem;                     // [36][64]
    float* Cs = (float*)(smem + 9216);            // [36][37]
    float* ny = (float*)(smem + 48128);
    float* sA = (float*)(smem + 48288);           // [36]
    float* sF = (float*)(smem + 49536);
    float* sG = (float*)(smem + 50560);
    const float* Yg = ir + (long)b * 36 * 64;
    for (int idx = tid; idx < 576; idx += 1024) {
      int row = idx >> 4, q4 = idx & 15;
      *(f32x4*)(Ys + row * 64 + q4 * 4) = *(const f32x4*)(Yg + row * 64 + q4 * 4);
    }
    __syncthreads();
    if (tid < 36) {
      float a = 0.f;
#pragma unroll
      for (int q4 = 0; q4 < 13; ++q4) {
        f32x4 v = *(const f32x4*)(Ys + tid * 64 + q4 * 4);
        a += v[0]*v[0] + v[1]*v[1] + v[2]*v[2] + v[3]*v[3];
      }
      ny[tid] = a;
    }
    __syncthreads();
    if (tid < 1008) {
      int ii = tid / 36, jj = tid - ii * 36;
      f32x4 yr[13];
#pragma unroll
      for (int q4 = 0; q4 < 13; ++q4) yr[q4] = *(const f32x4*)(Ys + jj * 64 + q4 * 4);
      float nyj = ny[jj];
      for (int i = ii; i < 36; i += 28) {
        float d = 0.f;
#pragma unroll
        for (int q4 = 0; q4 < 13; ++q4) {
          f32x4 xv = *(const f32x4*)(Ys + i * 64 + q4 * 4);
          d += xv[0]*yr[q4][0] + xv[1]*yr[q4][1] + xv[2]*yr[q4][2] + xv[3]*yr[q4][3];
        }
        Cs[i * 37 + jj] = (d - 0.5f * (ny[i] + nyj)) * INV_EPS_LN2;
      }
    }
    __syncthreads();
    int j = tid >> 2, kk = tid & 3;
    float Creg[9];
    if (j < 36) {
#pragma unroll
      for (int t = 0; t < 9; ++t) {
        int i2 = kk * 9 + t;
        Creg[t] = (i2 < 36) ? Cs[i2 * 37 + j] : 0.f;
      }
    }
    if (tid < 36) { sF[tid] = 0.f; sA[tid] = -LOG2_36; }
    __syncthreads();
    for (int h = 0; h < 40; ++h) {
      float m = -1e30f;
      if (j < 36) {
#pragma unroll
        for (int t = 0; t < 9; ++t) {
          int i2 = kk * 9 + t;
          if (i2 < 36) m = fmaxf(m, sA[i2] + Creg[t]);
        }
        m = fmaxf(m, __shfl_xor(m, 1)); m = fmaxf(m, __shfl_xor(m, 2));
      }
      __syncthreads();
      if (j < 36 && kk == 0) {
        ((h & 1) ? sF : sG)[j] = -EPS_LN2 * m;
        sA[j] = -LOG2_36 - m;
      }
      __syncthreads();
    }
    if (tid < 64) {
      float a = (tid < 36) ? sF[tid] + sG[tid] : 0.f;
#pragma unroll
      for (int o = 1; o < 64; o <<= 1) a += __shfl_xor(a, o);
      if (tid == 0) Syy[b] = a / 36.f;
    }
  }
}

// ---------------------------------------------------------------------------
// Final combine: w_dis -> w_pred, max with mix_pred, 2-way softmax.
// ---------------------------------------------------------------------------
__global__ void k_final(const float* __restrict__ mix, const float* __restrict__ sxy,
                        const float* __restrict__ sxx, const float* __restrict__ syy,
                        float* __restrict__ out) {
  int b = blockIdx.x * 64 + threadIdx.x;
  if (b < 128) {
    float w  = sxy[b] - 0.5f * (sxx[b] + syy[b]);
    float x0 = fmaxf(mix[b * 2 + 0], 1.0f - 0.01f * w);
    float x1 = fmaxf(mix[b * 2 + 1], 0.01f * w);
    float mx = fmaxf(x0, x1);
    float e0 = expf(x0 - mx), e1 = expf(x1 - mx);
    float inv = 1.f / (e0 + e1);
    out[b * 2 + 0] = e0 * inv;
    out[b * 2 + 1] = e1 * inv;
  }
}

// ---------------------------------------------------------------------------
extern "C" void kernel_launch(void* const* d_in, const int* in_sizes, int n_in,
                              void* d_out, int out_size, void* d_ws, size_t ws_size,
                              hipStream_t stream) {
  const float* txt_global = (const float*)d_in[0];
  const float* txt_region = (const float*)d_in[1];
  const float* img_global = (const float*)d_in[2];
  const float* img_region = (const float*)d_in[3];
  const float* social     = (const float*)d_in[4];
  const int*   attn_mask  = (const int*)  d_in[5];
  const float* W_stat = (const float*)d_in[6];  const float* b_stat = (const float*)d_in[7];
  const float* W_gt   = (const float*)d_in[8];  const float* b_gt   = (const float*)d_in[9];
  const float* W_gi   = (const float*)d_in[10]; const float* b_gi   = (const float*)d_in[11];
  const float* W_rt   = (const float*)d_in[12]; const float* b_rt   = (const float*)d_in[13];
  const float* W_ri   = (const float*)d_in[14]; const float* b_ri   = (const float*)d_in[15];
  const float* W_m1   = (const float*)d_in[16]; const float* b_m1   = (const float*)d_in[17];
  const float* W_m2   = (const float*)d_in[18]; const float* b_m2   = (const float*)d_in[19];

  float* ws = (float*)d_ws;
  float* ws_mix = ws;                    // 256
  float* ws_sxy = ws + 256;              // 128
  float* ws_sxx = ws + 384;              // 128
  float* ws_syy = ws + 512;              // 128
  short* ws_frt = (short*)(ws + 1024);   // 49152 shorts -> ends float 25600
  short* ws_fri = (short*)(ws + 25600);  // 131072 shorts -> ends float 91136
  float* ws_tr  = ws + 131072;           // [32768][64]
  float* ws_ir  = ws + 2228224;          // [4608][64]
  float* ws_cxx = ws + 2523136;          // [128][256][256]
  float* ws_pre = ws_cxx;                // [23][128][200]; consumed by k_pm
                                         // before k_sink overwrites with Cxx

  k_prep<<<456, 256, 0, stream>>>(W_rt, W_ri, ws_frt, ws_fri,
                                  txt_global, img_global, social,
                                  W_stat, b_stat, W_gt, W_gi, ws_pre);
  k_pm<<<712, 256, 0, stream>>>(txt_region, ws_frt, b_rt, ws_tr,
                                img_region, ws_fri, b_ri, ws_ir,
                                ws_pre, b_gt, b_gi,
                                W_m1, b_m1, W_m2, b_m2, ws_mix);
  k_sink<<<384, 1024, 0, stream>>>(ws_tr, ws_ir, attn_mask, ws_cxx,
                                   ws_sxy, ws_sxx, ws_syy);
  k_final<<<2, 64, 0, stream>>>(ws_mix, ws_sxy, ws_sxx, ws_syy, (float*)d_out);
}

// Round 4
// 327.252 us; speedup vs baseline: 1.0269x; 1.0269x over previous
//
#include <hip/hip_runtime.h>

typedef float  f32x4 __attribute__((ext_vector_type(4)));
typedef short  s16x8 __attribute__((ext_vector_type(8)));

#define EPS_LN2      0.0017328679513998632f   /* eps*ln2, eps = 0.0025 */
#define INV_EPS_LN2  577.0780163555852f       /* 1/(eps*ln2) */
#define LOG2_36      5.169925001442312f

__device__ __forceinline__ short f2bf(float x) {
  unsigned int u; __builtin_memcpy(&u, &x, 4);
  u = (u + 0x7FFFu + ((u >> 16) & 1u)) >> 16;   // RNE
  return (short)u;
}

// ---------------------------------------------------------------------------
// k_prep: blocks [0,88) pack W_rt/W_ri into MFMA B-frag order (bf16);
// blocks [88,456) K-split GEMM writing per-job slices pre[23][128][200].
// ---------------------------------------------------------------------------
__global__ __launch_bounds__(256) void k_prep(
    const float* __restrict__ W_rt, const float* __restrict__ W_ri,
    short* __restrict__ frt, short* __restrict__ fri,
    const float* __restrict__ txt, const float* __restrict__ img,
    const float* __restrict__ social,
    const float* __restrict__ W_stat, const float* __restrict__ b_stat,
    const float* __restrict__ W_gt, const float* __restrict__ W_gi,
    float* __restrict__ pre) {
  __shared__ float sA[32][128];
  int bid = blockIdx.x;
  if (bid < 88) {
    int slot = bid * 256 + threadIdx.x;   // 22528 total
    const float* W; short* dst; int f;
    if (slot < 6144) { W = W_rt; dst = frt; f = slot; }
    else             { W = W_ri; dst = fri; f = slot - 6144; }
    int k32 = f >> 8, rem = f & 255, ct = rem >> 6, l = rem & 63;
    int col = ct * 16 + (l & 15);
    int k0  = k32 * 32 + (l >> 4) * 8;
    s16x8 p;
#pragma unroll
    for (int c = 0; c < 8; ++c) {
      float v = (col < 50) ? W[(k0 + c) * 50 + col] : 0.f;
      p[c] = f2bf(v);
    }
    *(s16x8*)(dst + (long)f * 8) = p;
    return;
  }
  int gb = bid - 88;
  int job = gb >> 4, rb = (gb >> 2) & 3, cb = gb & 3;
  int t = threadIdx.x, r0 = rb * 32;
  const float* W; int k0, klen;
  if (job < 6)       { k0 = job * 128;       klen = 128; W = W_gt; }
  else if (job == 6) { k0 = 0;               klen = 100; W = W_gt + 768 * 200; }
  else               { k0 = (job - 7) * 128; klen = 128; W = W_gi; }
  if (job == 6) {
    for (int idx = t; idx < 4096; idx += 256) {
      int r = idx >> 7, k = idx & 127;
      float v = 0.f;
      if (k < 100) {
        v = b_stat[k];
#pragma unroll
        for (int u = 0; u < 10; ++u) v += social[(r0 + r) * 10 + u] * W_stat[u * 100 + k];
        v = fmaxf(v, 0.f);
      }
      sA[r][k] = v;
    }
  } else {
    const float* A = (job < 6) ? txt : img;
    int K_A = (job < 6) ? 768 : 2048;
    for (int idx = t; idx < 4096; idx += 256) {
      int r = idx >> 7, k = idx & 127;
      sA[r][k] = A[(r0 + r) * K_A + k0 + k];
    }
  }
  __syncthreads();
  int c = cb * 64 + (t & 63), rg = t >> 6;
  if (c < 200) {
    float acc[8];
#pragma unroll
    for (int i = 0; i < 8; ++i) acc[i] = 0.f;
    for (int k4 = 0; k4 < klen; k4 += 4) {
      float w0 = W[(k0 + k4    ) * 200 + c];
      float w1 = W[(k0 + k4 + 1) * 200 + c];
      float w2 = W[(k0 + k4 + 2) * 200 + c];
      float w3 = W[(k0 + k4 + 3) * 200 + c];
#pragma unroll
      for (int i = 0; i < 8; ++i) {
        f32x4 a = *(const f32x4*)&sA[rg * 8 + i][k4];
        acc[i] += a[0]*w0 + a[1]*w1 + a[2]*w2 + a[3]*w3;
      }
    }
    float* dst = pre + (long)job * 25600;
#pragma unroll
    for (int i = 0; i < 8; ++i)
      dst[(r0 + rg * 8 + i) * 200 + c] = acc[i];
  }
}

// ---------------------------------------------------------------------------
// Projection GEMM, pure-TLP: one wave = 16 rows x K/4 (K-split-4 across the
// 4 waves of a block, LDS reduce at the end, NO barriers in the main loop).
// Loads issue JIT each iteration; latency is hidden by occupancy:
// __launch_bounds__(256,8) -> <=64 VGPR -> 8 blocks/CU, and the grid is
// 2464 blocks (~9.6/CU). B-frags are L2-resident, read direct from global.
// out[M][64] = relu(A[M][K] @ W + bias).
// ---------------------------------------------------------------------------
template<int K32>
__device__ __forceinline__ void proj_body(const float* __restrict__ A,
                                          const short* __restrict__ Bf,
                                          const float* __restrict__ bias,
                                          float* __restrict__ out, int bid,
                                          f32x4* __restrict__ red) {
  constexpr int KQ = K32 / 4;               // k32 steps per wave
  int wave = threadIdx.x >> 6, lane = threadIdx.x & 63;
  int rl = lane & 15, q = lane >> 4;
  int row0 = bid * 16;
  const int K = K32 * 32;
  const float* ar = A + (long)(row0 + rl) * K + wave * (KQ * 32) + q * 8;
  const s16x8* bp = (const s16x8*)Bf + wave * (KQ * 256) + lane;

  f32x4 acc[4];
#pragma unroll
  for (int ct = 0; ct < 4; ++ct) acc[ct] = (f32x4){0.f, 0.f, 0.f, 0.f};

#pragma unroll 2
  for (int k = 0; k < KQ; ++k) {
    f32x4 a0 = *(const f32x4*)(ar + k * 32);
    f32x4 a1 = *(const f32x4*)(ar + k * 32 + 4);
    const s16x8* p = bp + k * 256;
    s16x8 b0 = p[0], b1 = p[64], b2 = p[128], b3 = p[192];
    s16x8 af;
    af[0]=f2bf(a0[0]); af[1]=f2bf(a0[1]); af[2]=f2bf(a0[2]); af[3]=f2bf(a0[3]);
    af[4]=f2bf(a1[0]); af[5]=f2bf(a1[1]); af[6]=f2bf(a1[2]); af[7]=f2bf(a1[3]);
    acc[0] = __builtin_amdgcn_mfma_f32_16x16x32_bf16(af, b0, acc[0], 0, 0, 0);
    acc[1] = __builtin_amdgcn_mfma_f32_16x16x32_bf16(af, b1, acc[1], 0, 0, 0);
    acc[2] = __builtin_amdgcn_mfma_f32_16x16x32_bf16(af, b2, acc[2], 0, 0, 0);
    acc[3] = __builtin_amdgcn_mfma_f32_16x16x32_bf16(af, b3, acc[3], 0, 0, 0);
  }

  // ---- K-split reduction: waves 1..3 dump, wave 0 combines + writes ----
  if (wave) {
#pragma unroll
    for (int ct = 0; ct < 4; ++ct)
      red[((wave - 1) * 4 + ct) * 64 + lane] = acc[ct];
  }
  __syncthreads();
  if (wave == 0) {
#pragma unroll
    for (int ct = 0; ct < 4; ++ct) {
      f32x4 s = acc[ct];
#pragma unroll
      for (int w = 0; w < 3; ++w) s = s + red[(w * 4 + ct) * 64 + lane];
      int col = ct * 16 + rl;
      float bv = (col < 50) ? bias[col] : 0.f;
#pragma unroll
      for (int r = 0; r < 4; ++r) {
        int grow = row0 + q * 4 + r;           // D row = quad*4+reg (m89)
        float v = fmaxf(s[r] + bv, 0.f);
        out[(long)grow * 64 + col] = (col < 50) ? v : 0.f;
      }
    }
  }
}

// MLP tail body: one block per batch row; sums the 23 per-job GEMM slices.
__device__ __forceinline__ void mix_body(
    int r, const float* __restrict__ pre,
    const float* __restrict__ b_gt, const float* __restrict__ b_gi,
    const float* __restrict__ W_m1, const float* __restrict__ b_m1,
    const float* __restrict__ W_m2, const float* __restrict__ b_m2,
    float* __restrict__ mix, float* smem) {
  float* sm = smem;            // [200]
  float* sh = smem + 200;      // [100]
  int t = threadIdx.x;
  if (t < 200) {
    float s1 = b_gt[t], s2 = b_gi[t];
#pragma unroll
    for (int j = 0; j < 7; ++j)  s1 += pre[(long)j * 25600 + r * 200 + t];
#pragma unroll
    for (int j = 7; j < 23; ++j) s2 += pre[(long)j * 25600 + r * 200 + t];
    sm[t] = fmaxf(s1, 0.f) + fmaxf(s2, 0.f);
  }
  __syncthreads();
  if (t < 100) {
    float a = b_m1[t];
#pragma unroll 4
    for (int k = 0; k < 200; ++k) a += sm[k] * W_m1[k * 100 + t];
    sh[t] = fmaxf(a, 0.f);
  }
  __syncthreads();
  if (t < 2) {
    float a = b_m2[t];
    for (int k = 0; k < 100; ++k) a += sh[k] * W_m2[k * 2 + t];
    mix[r * 2 + t] = a;
  }
}

// Grid order: img proj [0,288) first (longest: 16 iters/wave), txt proj
// [288,2336), mix [2336,2464) last (tiny).
__global__ __launch_bounds__(256, 8)
void k_pm(
    const float* __restrict__ txt_region, const short* __restrict__ frt,
    const float* __restrict__ b_rt, float* __restrict__ tr,
    const float* __restrict__ img_region, const short* __restrict__ fri,
    const float* __restrict__ b_ri, float* __restrict__ ir,
    const float* __restrict__ pre,
    const float* __restrict__ b_gt, const float* __restrict__ b_gi,
    const float* __restrict__ W_m1, const float* __restrict__ b_m1,
    const float* __restrict__ W_m2, const float* __restrict__ b_m2,
    float* __restrict__ mix) {
  __shared__ __align__(16) f32x4 red[768];   // 12 KB
  int bid = blockIdx.x;
  if (bid < 288)       proj_body<64>(img_region, fri, b_ri, ir, bid, red);
  else if (bid < 2336) proj_body<24>(txt_region, frt, b_rt, tr, bid - 288, red);
  else                 mix_body(bid - 2336, pre, b_gt, b_gi, W_m1, b_m1, W_m2, b_m2, mix, (float*)red);
}

// ---------------------------------------------------------------------------
// Merged Sinkhorn kernel, MAX-PLUS. role 0: xx (n x n), role 1: xy (n x 36),
// role 2: yy (36 x 36). XX holds its C column-slice in 16 named f32x4 regs,
// pinned with an opaque asm so the compiler cannot re-load from global.
// waves_per_eu(4,12): min 4 keeps the 128-VGPR budget, max 12 allows 3
// blocks/CU (round-3's (4,4) CAPPED residency at 1 block/CU -> a serial
// second round of 128 blocks = the 0.65%-occupancy tail).
// ---------------------------------------------------------------------------
#define SK_SMEM 50736

__global__ __launch_bounds__(1024)
__attribute__((amdgpu_waves_per_eu(4, 12)))
void k_sink(
    const float* __restrict__ tr, const float* __restrict__ ir,
    const int* __restrict__ amask, float* __restrict__ Cxx,
    float* __restrict__ Sxy, float* __restrict__ Sxx, float* __restrict__ Syy) {
  __shared__ __align__(16) char smem[SK_SMEM];
  int role = blockIdx.x >> 7;
  int b    = blockIdx.x & 127;
  int tid  = threadIdx.x;

  if (role == 0) {
    // ====================== XX ======================
    short* Xf    = (short*)smem;                 // 32 KB
    float* norms = (float*)(smem + 32768);       // [256]
    float* sA    = (float*)(smem + 33792);       // [256]
    float* sF    = (float*)(smem + 34816);       // [256]
    float* sG    = (float*)(smem + 35840);       // [256]
    float* sPm   = (float*)(smem + 36864);       // [4][256]
    int*   nsh   = (int*)  (smem + 40960);
    if (tid < 64) {
      int c = 0;
      for (int i = tid; i < 256; i += 64) c += amask[b * 256 + i];
#pragma unroll
      for (int o = 1; o < 64; o <<= 1) c += __shfl_xor(c, o);
      if (tid == 0) *nsh = c;
    }
    const float* Xg = tr + (long)b * 256 * 64;
    for (int slot = tid; slot < 2048; slot += 1024) {
      int t = slot >> 7, k32 = (slot >> 6) & 1, l = slot & 63;
      int row = t * 16 + (l & 15), k0 = k32 * 32 + (l >> 4) * 8;
      const float* src = Xg + row * 64 + k0;
      f32x4 a0 = *(const f32x4*)src, a1 = *(const f32x4*)(src + 4);
      s16x8 p;
      p[0]=f2bf(a0[0]); p[1]=f2bf(a0[1]); p[2]=f2bf(a0[2]); p[3]=f2bf(a0[3]);
      p[4]=f2bf(a1[0]); p[5]=f2bf(a1[1]); p[6]=f2bf(a1[2]); p[7]=f2bf(a1[3]);
      *(s16x8*)(Xf + slot * 8) = p;
    }
    __syncthreads();
    int n = *nsh;
    // G = X X^T via MFMA. wave wv owns 16-row strip.
    int wv = tid >> 6, lane = tid & 63, q = lane >> 4;
    f32x4 acc[16];
#pragma unroll
    for (int ct = 0; ct < 16; ++ct) acc[ct] = (f32x4){0.f, 0.f, 0.f, 0.f};
    s16x8 afr0 = *(const s16x8*)(Xf + ((wv * 2 + 0) * 64 + lane) * 8);
    s16x8 afr1 = *(const s16x8*)(Xf + ((wv * 2 + 1) * 64 + lane) * 8);
#pragma unroll
    for (int ct = 0; ct < 16; ++ct) {
      s16x8 b0 = *(const s16x8*)(Xf + ((ct * 2 + 0) * 64 + lane) * 8);
      s16x8 b1 = *(const s16x8*)(Xf + ((ct * 2 + 1) * 64 + lane) * 8);
      acc[ct] = __builtin_amdgcn_mfma_f32_16x16x32_bf16(afr0, b0, acc[ct], 0, 0, 0);
      acc[ct] = __builtin_amdgcn_mfma_f32_16x16x32_bf16(afr1, b1, acc[ct], 0, 0, 0);
    }
#pragma unroll
    for (int r = 0; r < 4; ++r) {                 // diag of tile (wv,wv) = ||x||^2
      int m_ = q * 4 + r;
      if ((lane & 15) == m_) norms[wv * 16 + m_] = acc[wv][r];
    }
    __syncthreads();
    float* Cwb = Cxx + (long)b * 65536;           // D = -C/(eps ln2), f32, global
    if (wv * 16 < n) {                            // skip row-tiles entirely >= n
#pragma unroll
      for (int ct = 0; ct < 16; ++ct) {
        int gj = ct * 16 + (lane & 15);
        float nj = norms[gj];
#pragma unroll
        for (int r = 0; r < 4; ++r) {
          int gi = wv * 16 + q * 4 + r;
          Cwb[gi * 256 + gj] = (acc[ct][r] - 0.5f * (norms[gi] + nj)) * INV_EPS_LN2;
        }
      }
    }
    __syncthreads();
    // kk wave-uniform so prefix-skipping has no divergence
    int kk = tid >> 8, j = tid & 255, i0 = kk * 64;
    int iend = n - i0; if (iend > 64) iend = 64;
    f32x4 c0, c1, c2, c3, c4, c5, c6, c7, c8, c9, ca, cb, cc, cd, ce, cf;
    if (i0 < n) {                                 // wave-uniform chunk guard
      const float* cp = Cwb + (long)i0 * 256 + j;
#define XXLD(CV, T0) \
      CV[0] = cp[(T0+0)*256]; CV[1] = cp[(T0+1)*256]; \
      CV[2] = cp[(T0+2)*256]; CV[3] = cp[(T0+3)*256];
      XXLD(c0, 0)  XXLD(c1, 4)  XXLD(c2, 8)  XXLD(c3, 12)
      XXLD(c4, 16) XXLD(c5, 20) XXLD(c6, 24) XXLD(c7, 28)
      XXLD(c8, 32) XXLD(c9, 36) XXLD(ca, 40) XXLD(cb, 44)
      XXLD(cc, 48) XXLD(cd, 52) XXLD(ce, 56) XXLD(cf, 60)
#undef XXLD
      // opaque pin: values no longer provably == memory -> no remat/reload
      asm volatile("" : "+v"(c0), "+v"(c1), "+v"(c2), "+v"(c3),
                        "+v"(c4), "+v"(c5), "+v"(c6), "+v"(c7),
                        "+v"(c8), "+v"(c9), "+v"(ca), "+v"(cb),
                        "+v"(cc), "+v"(cd), "+v"(ce), "+v"(cf));
    }
    float log2n = log2f((float)n);
    if (tid < 256) { sF[tid] = 0.f; sA[tid] = (tid < n) ? -log2n : -1e30f; }
    __syncthreads();
    const float* ap2 = sA + i0;
#define XXG(CA, CB, CC, CD, OFF) { \
      f32x4 A0 = *(const f32x4*)(ap2 + OFF); \
      f32x4 A1 = *(const f32x4*)(ap2 + OFF + 4); \
      f32x4 A2 = *(const f32x4*)(ap2 + OFF + 8); \
      f32x4 A3 = *(const f32x4*)(ap2 + OFF + 12); \
      float x0 = A0[0]+CA[0], x1 = A0[1]+CA[1], x2 = A0[2]+CA[2], x3 = A0[3]+CA[3]; \
      float x4 = A1[0]+CB[0], x5 = A1[1]+CB[1], x6 = A1[2]+CB[2], x7 = A1[3]+CB[3]; \
      float x8 = A2[0]+CC[0], x9 = A2[1]+CC[1], xa = A2[2]+CC[2], xb = A2[3]+CC[3]; \
      float xc = A3[0]+CD[0], xd = A3[1]+CD[1], xe = A3[2]+CD[2], xf = A3[3]+CD[3]; \
      float y0 = fmaxf(fmaxf(x0, x1), x2); \
      float y1 = fmaxf(fmaxf(x3, x4), x5); \
      float y2 = fmaxf(fmaxf(x6, x7), x8); \
      float y3 = fmaxf(fmaxf(x9, xa), xb); \
      float y4 = fmaxf(fmaxf(xc, xd), xe); \
      m = fmaxf(m, fmaxf(fmaxf(fmaxf(y0, y1), fmaxf(y2, y3)), fmaxf(y4, xf))); }
    for (int h = 0; h < 40; ++h) {
      float m = -1e30f;
      if (i0 < n && j < n) {
        XXG(c0, c1, c2, c3, 0)
        if (iend > 16) { XXG(c4, c5, c6, c7, 16) }
        if (iend > 32) { XXG(c8, c9, ca, cb, 32) }
        if (iend > 48) { XXG(cc, cd, ce, cf, 48) }
      }
      sPm[kk * 256 + j] = m;
      __syncthreads();
      if (tid < 256) {
        float m4 = fmaxf(fmaxf(sPm[tid], sPm[256 + tid]),
                         fmaxf(sPm[512 + tid], sPm[768 + tid]));
        if (tid < n) {
          ((h & 1) ? sF : sG)[tid] = -EPS_LN2 * m4;
          sA[tid] = -log2n - m4;
        }
      }
      __syncthreads();
    }
#undef XXG
    if (tid < 64) {
      float a = 0.f;
      for (int i = tid; i < n; i += 64) a += sF[i] + sG[i];
#pragma unroll
      for (int o = 1; o < 64; o <<= 1) a += __shfl_xor(a, o);
      if (tid == 0) Sxx[b] = a / n;
    }
  } else if (role == 1) {
    // ====================== XY ======================
    float* Ys  = (float*)smem;                    // [36][64]
    float* Cs  = (float*)(smem + 9216);           // [256][37]
    float* nx  = (float*)(smem + 47104);          // [256]
    float* ny  = (float*)(smem + 48128);          // [36]
    float* sA  = (float*)(smem + 48288);          // padded alpha [272]
    float* sB  = (float*)(smem + 49376);          // beta [36]
    float* sF  = (float*)(smem + 49536);          // [256]
    float* sG  = (float*)(smem + 50560);          // [36]
    int*   nsh = (int*)  (smem + 50720);
    if (tid < 64) {
      int c = 0;
      for (int i = tid; i < 256; i += 64) c += amask[b * 256 + i];
#pragma unroll
      for (int o = 1; o < 64; o <<= 1) c += __shfl_xor(c, o);
      if (tid == 0) *nsh = c;
    }
    const float* Xg = tr + (long)b * 256 * 64;
    const float* Yg = ir + (long)b * 36 * 64;
    for (int idx = tid; idx < 576; idx += 1024) {
      int row = idx >> 4, q4 = idx & 15;
      *(f32x4*)(Ys + row * 64 + q4 * 4) = *(const f32x4*)(Yg + row * 64 + q4 * 4);
    }
    __syncthreads();
    int n = *nsh;
    if (tid < 256) {
      float a = 0.f;
#pragma unroll
      for (int q4 = 0; q4 < 13; ++q4) {
        f32x4 v = *(const f32x4*)(Xg + tid * 64 + q4 * 4);
        a += v[0]*v[0] + v[1]*v[1] + v[2]*v[2] + v[3]*v[3];
      }
      nx[tid] = a;
    } else if (tid < 292) {
      int jj = tid - 256; float a = 0.f;
#pragma unroll
      for (int q4 = 0; q4 < 13; ++q4) {
        f32x4 v = *(const f32x4*)(Ys + jj * 64 + q4 * 4);
        a += v[0]*v[0] + v[1]*v[1] + v[2]*v[2] + v[3]*v[3];
      }
      ny[jj] = a;
    }
    __syncthreads();
    if (tid < 1008) {
      int ii = tid / 36, jj = tid - ii * 36;
      f32x4 yr[13];
#pragma unroll
      for (int q4 = 0; q4 < 13; ++q4) yr[q4] = *(const f32x4*)(Ys + jj * 64 + q4 * 4);
      float nyj = ny[jj];
      for (int i = ii; i < 256; i += 28) {
        float d = 0.f;
#pragma unroll
        for (int q4 = 0; q4 < 13; ++q4) {
          f32x4 xv = *(const f32x4*)(Xg + i * 64 + q4 * 4);
          d += xv[0]*yr[q4][0] + xv[1]*yr[q4][1] + xv[2]*yr[q4][2] + xv[3]*yr[q4][3];
        }
        Cs[i * 37 + jj] = (d - 0.5f * (nx[i] + nyj)) * INV_EPS_LN2;
      }
    }
    __syncthreads();
    int jg = tid >> 4, kg = tid & 15;             // g-role: column jg, slice kg
    float Cg[16];
    if (jg < 36) {
#pragma unroll
      for (int t = 0; t < 16; ++t) Cg[t] = Cs[(kg * 16 + t) * 37 + jg];
    }
    int fi = tid >> 2, kf = tid & 3;              // f-role: row fi, slice kf
    float Cf[9];
#pragma unroll
    for (int t = 0; t < 9; ++t) {
      int jj2 = kf * 9 + t;
      Cf[t] = (jj2 < 36) ? Cs[fi * 37 + jj2] : 0.f;
    }
    float log2n = log2f((float)n);
    if (tid < 256) { sF[tid] = 0.f; sA[tid + (tid >> 4)] = -log2n; }
    __syncthreads();
    const float* agp = sA + kg * 17;
    int gend = n - kg * 16; if (gend > 16) gend = 16;
    for (int it = 0; it < 20; ++it) {
      float gm = -1e30f;
      if (jg < 36) {
#pragma unroll
        for (int t = 0; t < 16; ++t)
          if (t < gend) gm = fmaxf(gm, agp[t] + Cg[t]);
        gm = fmaxf(gm, __shfl_xor(gm, 1)); gm = fmaxf(gm, __shfl_xor(gm, 2));
        gm = fmaxf(gm, __shfl_xor(gm, 4)); gm = fmaxf(gm, __shfl_xor(gm, 8));
      }
      __syncthreads();
      if (jg < 36 && kg == 0) {
        sG[jg] = -EPS_LN2 * gm;
        sB[jg] = -LOG2_36 - gm;
      }
      __syncthreads();
      float fm = -1e30f;
#pragma unroll
      for (int t = 0; t < 9; ++t) {
        int jj2 = kf * 9 + t;
        if (jj2 < 36) fm = fmaxf(fm, sB[jj2] + Cf[t]);
      }
      fm = fmaxf(fm, __shfl_xor(fm, 1)); fm = fmaxf(fm, __shfl_xor(fm, 2));
      __syncthreads();
      if (kf == 0 && fi < n) {
        sF[fi] = -EPS_LN2 * fm;
        sA[fi + (fi >> 4)] = -log2n - fm;
      }
      __syncthreads();
    }
    if (tid < 64) {
      float a = 0.f;
      for (int i = tid; i < n; i += 64) a += sF[i];
      float g = (tid < 36) ? sG[tid] : 0.f;
#pragma unroll
      for (int o = 1; o < 64; o <<= 1) { a += __shfl_xor(a, o); g += __shfl_xor(g, o); }
      if (tid == 0) Sxy[b] = a / n + g / 36.f;
    }
  } else {
    // ====================== YY ======================
    float* Ys = (float*)smem;                     // [36][64]
    float* Cs = (float*)(smem + 9216);            // [36][37]
    float* ny = (float*)(smem + 48128);
    float* sA = (float*)(smem + 48288);           // [36]
    float* sF = (float*)(smem + 49536);
    float* sG = (float*)(smem + 50560);
    const float* Yg = ir + (long)b * 36 * 64;
    for (int idx = tid; idx < 576; idx += 1024) {
      int row = idx >> 4, q4 = idx & 15;
      *(f32x4*)(Ys + row * 64 + q4 * 4) = *(const f32x4*)(Yg + row * 64 + q4 * 4);
    }
    __syncthreads();
    if (tid < 36) {
      float a = 0.f;
#pragma unroll
      for (int q4 = 0; q4 < 13; ++q4) {
        f32x4 v = *(const f32x4*)(Ys + tid * 64 + q4 * 4);
        a += v[0]*v[0] + v[1]*v[1] + v[2]*v[2] + v[3]*v[3];
      }
      ny[tid] = a;
    }
    __syncthreads();
    if (tid < 1008) {
      int ii = tid / 36, jj = tid - ii * 36;
      f32x4 yr[13];
#pragma unroll
      for (int q4 = 0; q4 < 13; ++q4) yr[q4] = *(const f32x4*)(Ys + jj * 64 + q4 * 4);
      float nyj = ny[jj];
      for (int i = ii; i < 36; i += 28) {
        float d = 0.f;
#pragma unroll
        for (int q4 = 0; q4 < 13; ++q4) {
          f32x4 xv = *(const f32x4*)(Ys + i * 64 + q4 * 4);
          d += xv[0]*yr[q4][0] + xv[1]*yr[q4][1] + xv[2]*yr[q4][2] + xv[3]*yr[q4][3];
        }
        Cs[i * 37 + jj] = (d - 0.5f * (ny[i] + nyj)) * INV_EPS_LN2;
      }
    }
    __syncthreads();
    int j = tid >> 2, kk = tid & 3;
    float Creg[9];
    if (j < 36) {
#pragma unroll
      for (int t = 0; t < 9; ++t) {
        int i2 = kk * 9 + t;
        Creg[t] = (i2 < 36) ? Cs[i2 * 37 + j] : 0.f;
      }
    }
    if (tid < 36) { sF[tid] = 0.f; sA[tid] = -LOG2_36; }
    __syncthreads();
    for (int h = 0; h < 40; ++h) {
      float m = -1e30f;
      if (j < 36) {
#pragma unroll
        for (int t = 0; t < 9; ++t) {
          int i2 = kk * 9 + t;
          if (i2 < 36) m = fmaxf(m, sA[i2] + Creg[t]);
        }
        m = fmaxf(m, __shfl_xor(m, 1)); m = fmaxf(m, __shfl_xor(m, 2));
      }
      __syncthreads();
      if (j < 36 && kk == 0) {
        ((h & 1) ? sF : sG)[j] = -EPS_LN2 * m;
        sA[j] = -LOG2_36 - m;
      }
      __syncthreads();
    }
    if (tid < 64) {
      float a = (tid < 36) ? sF[tid] + sG[tid] : 0.f;
#pragma unroll
      for (int o = 1; o < 64; o <<= 1) a += __shfl_xor(a, o);
      if (tid == 0) Syy[b] = a / 36.f;
    }
  }
}

// ---------------------------------------------------------------------------
// Final combine: w_dis -> w_pred, max with mix_pred, 2-way softmax.
// ---------------------------------------------------------------------------
__global__ void k_final(const float* __restrict__ mix, const float* __restrict__ sxy,
                        const float* __restrict__ sxx, const float* __restrict__ syy,
                        float* __restrict__ out) {
  int b = blockIdx.x * 64 + threadIdx.x;
  if (b < 128) {
    float w  = sxy[b] - 0.5f * (sxx[b] + syy[b]);
    float x0 = fmaxf(mix[b * 2 + 0], 1.0f - 0.01f * w);
    float x1 = fmaxf(mix[b * 2 + 1], 0.01f * w);
    float mx = fmaxf(x0, x1);
    float e0 = expf(x0 - mx), e1 = expf(x1 - mx);
    float inv = 1.f / (e0 + e1);
    out[b * 2 + 0] = e0 * inv;
    out[b * 2 + 1] = e1 * inv;
  }
}

// ---------------------------------------------------------------------------
extern "C" void kernel_launch(void* const* d_in, const int* in_sizes, int n_in,
                              void* d_out, int out_size, void* d_ws, size_t ws_size,
                              hipStream_t stream) {
  const float* txt_global = (const float*)d_in[0];
  const float* txt_region = (const float*)d_in[1];
  const float* img_global = (const float*)d_in[2];
  const float* img_region = (const float*)d_in[3];
  const float* social     = (const float*)d_in[4];
  const int*   attn_mask  = (const int*)  d_in[5];
  const float* W_stat = (const float*)d_in[6];  const float* b_stat = (const float*)d_in[7];
  const float* W_gt   = (const float*)d_in[8];  const float* b_gt   = (const float*)d_in[9];
  const float* W_gi   = (const float*)d_in[10]; const float* b_gi   = (const float*)d_in[11];
  const float* W_rt   = (const float*)d_in[12]; const float* b_rt   = (const float*)d_in[13];
  const float* W_ri   = (const float*)d_in[14]; const float* b_ri   = (const float*)d_in[15];
  const float* W_m1   = (const float*)d_in[16]; const float* b_m1   = (const float*)d_in[17];
  const float* W_m2   = (const float*)d_in[18]; const float* b_m2   = (const float*)d_in[19];

  float* ws = (float*)d_ws;
  float* ws_mix = ws;                    // 256
  float* ws_sxy = ws + 256;              // 128
  float* ws_sxx = ws + 384;              // 128
  float* ws_syy = ws + 512;              // 128
  short* ws_frt = (short*)(ws + 1024);   // 49152 shorts -> ends float 25600
  short* ws_fri = (short*)(ws + 25600);  // 131072 shorts -> ends float 91136
  float* ws_tr  = ws + 131072;           // [32768][64]
  float* ws_ir  = ws + 2228224;          // [4608][64]
  float* ws_cxx = ws + 2523136;          // [128][256][256]
  float* ws_pre = ws_cxx;                // [23][128][200]; consumed by k_pm
                                         // before k_sink overwrites with Cxx

  k_prep<<<456, 256, 0, stream>>>(W_rt, W_ri, ws_frt, ws_fri,
                                  txt_global, img_global, social,
                                  W_stat, b_stat, W_gt, W_gi, ws_pre);
  k_pm<<<2464, 256, 0, stream>>>(txt_region, ws_frt, b_rt, ws_tr,
                                 img_region, ws_fri, b_ri, ws_ir,
                                 ws_pre, b_gt, b_gi,
                                 W_m1, b_m1, W_m2, b_m2, ws_mix);
  k_sink<<<384, 1024, 0, stream>>>(ws_tr, ws_ir, attn_mask, ws_cxx,
                                   ws_sxy, ws_sxx, ws_syy);
  k_final<<<2, 64, 0, stream>>>(ws_mix, ws_sxy, ws_sxx, ws_syy, (float*)d_out);
}

// Round 6
// 326.413 us; speedup vs baseline: 1.0295x; 1.0026x over previous
//
#include <hip/hip_runtime.h>

typedef float        f32x4 __attribute__((ext_vector_type(4)));
typedef short        s16x8 __attribute__((ext_vector_type(8)));
typedef unsigned int u32x4 __attribute__((ext_vector_type(4)));

#define EPS_LN2      0.0017328679513998632f   /* eps*ln2, eps = 0.0025 */
#define INV_EPS_LN2  577.0780163555852f       /* 1/(eps*ln2) */
#define LOG2_36      5.169925001442312f

__device__ __forceinline__ short f2bf(float x) {
  unsigned int u; __builtin_memcpy(&u, &x, 4);
  u = (u + 0x7FFFu + ((u >> 16) & 1u)) >> 16;   // RNE
  return (short)u;
}

__device__ __forceinline__ unsigned short f2h(float x) {
  return __builtin_bit_cast(unsigned short, (_Float16)x);
}
__device__ __forceinline__ float h2f(unsigned short h) {
  return (float)__builtin_bit_cast(_Float16, h);
}

#define GLOAD16(g, l) __builtin_amdgcn_global_load_lds( \
    (const __attribute__((address_space(1))) void*)(g), \
    (__attribute__((address_space(3))) void*)(l), 16, 0, 0)

// ---------------------------------------------------------------------------
// k_prep: blocks [0,88) pack W_rt/W_ri into MFMA B-frag order (bf16);
// blocks [88,456) K-split GEMM writing per-job slices pre[23][128][200].
// ---------------------------------------------------------------------------
__global__ __launch_bounds__(256) void k_prep(
    const float* __restrict__ W_rt, const float* __restrict__ W_ri,
    short* __restrict__ frt, short* __restrict__ fri,
    const float* __restrict__ txt, const float* __restrict__ img,
    const float* __restrict__ social,
    const float* __restrict__ W_stat, const float* __restrict__ b_stat,
    const float* __restrict__ W_gt, const float* __restrict__ W_gi,
    float* __restrict__ pre) {
  __shared__ float sA[32][128];
  int bid = blockIdx.x;
  if (bid < 88) {
    int slot = bid * 256 + threadIdx.x;   // 22528 total
    const float* W; short* dst; int f;
    if (slot < 6144) { W = W_rt; dst = frt; f = slot; }
    else             { W = W_ri; dst = fri; f = slot - 6144; }
    int k32 = f >> 8, rem = f & 255, ct = rem >> 6, l = rem & 63;
    int col = ct * 16 + (l & 15);
    int k0  = k32 * 32 + (l >> 4) * 8;
    s16x8 p;
#pragma unroll
    for (int c = 0; c < 8; ++c) {
      float v = (col < 50) ? W[(k0 + c) * 50 + col] : 0.f;
      p[c] = f2bf(v);
    }
    *(s16x8*)(dst + (long)f * 8) = p;
    return;
  }
  int gb = bid - 88;
  int job = gb >> 4, rb = (gb >> 2) & 3, cb = gb & 3;
  int t = threadIdx.x, r0 = rb * 32;
  const float* W; int k0, klen;
  if (job < 6)       { k0 = job * 128;       klen = 128; W = W_gt; }
  else if (job == 6) { k0 = 0;               klen = 100; W = W_gt + 768 * 200; }
  else               { k0 = (job - 7) * 128; klen = 128; W = W_gi; }
  if (job == 6) {
    for (int idx = t; idx < 4096; idx += 256) {
      int r = idx >> 7, k = idx & 127;
      float v = 0.f;
      if (k < 100) {
        v = b_stat[k];
#pragma unroll
        for (int u = 0; u < 10; ++u) v += social[(r0 + r) * 10 + u] * W_stat[u * 100 + k];
        v = fmaxf(v, 0.f);
      }
      sA[r][k] = v;
    }
  } else {
    const float* A = (job < 6) ? txt : img;
    int K_A = (job < 6) ? 768 : 2048;
    for (int idx = t; idx < 4096; idx += 256) {
      int r = idx >> 7, k = idx & 127;
      sA[r][k] = A[(r0 + r) * K_A + k0 + k];
    }
  }
  __syncthreads();
  int c = cb * 64 + (t & 63), rg = t >> 6;
  if (c < 200) {
    float acc[8];
#pragma unroll
    for (int i = 0; i < 8; ++i) acc[i] = 0.f;
    for (int k4 = 0; k4 < klen; k4 += 4) {
      float w0 = W[(k0 + k4    ) * 200 + c];
      float w1 = W[(k0 + k4 + 1) * 200 + c];
      float w2 = W[(k0 + k4 + 2) * 200 + c];
      float w3 = W[(k0 + k4 + 3) * 200 + c];
#pragma unroll
      for (int i = 0; i < 8; ++i) {
        f32x4 a = *(const f32x4*)&sA[rg * 8 + i][k4];
        acc[i] += a[0]*w0 + a[1]*w1 + a[2]*w2 + a[3]*w3;
      }
    }
    float* dst = pre + (long)job * 25600;
#pragma unroll
    for (int i = 0; i < 8; ++i)
      dst[(r0 + rg * 8 + i) * 200 + c] = acc[i];
  }
}

// ---------------------------------------------------------------------------
// Projection GEMM: wave-private double-buffered LDS staging via
// global_load_lds (zero VGPR cost, counted vmcnt, NO barriers in the loop --
// the A-tile of a wave is private to that wave). A-source addresses are
// pre-swizzled on the GLOBAL side (the per-lane side) so the linear LDS dest
// reads back bank-uniform: LDS layout A[row][funit^(row&7)] (16B units).
// One block = 32 rows x 2 row-groups x 2 K-halves (4 waves), one end-reduce.
// out[M][64] = relu(A[M][K] @ W + bias).
// ---------------------------------------------------------------------------
template<int K32>
__device__ __forceinline__ void proj_body(const float* __restrict__ A,
                                          const short* __restrict__ Bf,
                                          const float* __restrict__ bias,
                                          float* __restrict__ out, int bid,
                                          char* smem) {
  constexpr int KH = K32 / 2;               // k32 steps per wave
  int wave = threadIdx.x >> 6, lane = threadIdx.x & 63;
  int rg = wave >> 1, ks = wave & 1;
  int rl = lane & 15, q = lane >> 4, r7 = rl & 7;
  int row0 = bid * 32 + rg * 16;
  const int K = K32 * 32;
  char* wbuf = smem + wave * 12288;         // [2 stages][A 2KB + B 4KB]

  // gload lane mapping: instr covers 8 rows; lane l -> row l>>3, pos l&7.
  // pos p holds funit p^(row&7)  (row&7 == l>>3 for both instrs).
  int ra = lane >> 3, pa = lane & 7;
  int fsw = (pa ^ ra) * 4;                  // float offset of swizzled funit
  const float* asrc0 = A + (long)(row0 + ra)     * K + ks * (KH * 32) + fsw;
  const float* asrc1 = A + (long)(row0 + 8 + ra) * K + ks * (KH * 32) + fsw;
  const short* bsrc  = Bf + (long)ks * (KH * 2048) + lane * 8;

#define PSTAGE(KK, ST) { \
    char* ad = wbuf + (ST) * 6144; \
    GLOAD16(asrc0 + (KK) * 32, ad); \
    GLOAD16(asrc1 + (KK) * 32, ad + 1024); \
    char* bd = ad + 2048; \
    const short* bs = bsrc + (KK) * 2048; \
    GLOAD16(bs,        bd); \
    GLOAD16(bs + 512,  bd + 1024); \
    GLOAD16(bs + 1024, bd + 2048); \
    GLOAD16(bs + 1536, bd + 3072); \
  }

  f32x4 acc[4];
#pragma unroll
  for (int ct = 0; ct < 4; ++ct) acc[ct] = (f32x4){0.f, 0.f, 0.f, 0.f};

  PSTAGE(0, 0);
#pragma unroll
  for (int k = 0; k < KH; ++k) {
    if (k + 1 < KH) {
      PSTAGE(k + 1, (k + 1) & 1);
      asm volatile("s_waitcnt vmcnt(6)" ::: "memory");   // stage k landed
    } else {
      asm volatile("s_waitcnt vmcnt(0)" ::: "memory");
    }
    __builtin_amdgcn_sched_barrier(0);
    const char* ab = wbuf + (k & 1) * 6144;
    f32x4 a0 = *(const f32x4*)(ab + rl * 128 + (((q * 2)     ^ r7) << 4));
    f32x4 a1 = *(const f32x4*)(ab + rl * 128 + (((q * 2 + 1) ^ r7) << 4));
    const char* bb = ab + 2048;
    s16x8 af;
    af[0]=f2bf(a0[0]); af[1]=f2bf(a0[1]); af[2]=f2bf(a0[2]); af[3]=f2bf(a0[3]);
    af[4]=f2bf(a1[0]); af[5]=f2bf(a1[1]); af[6]=f2bf(a1[2]); af[7]=f2bf(a1[3]);
#pragma unroll
    for (int ct = 0; ct < 4; ++ct) {
      s16x8 bfr = *(const s16x8*)(bb + ct * 1024 + lane * 16);
      acc[ct] = __builtin_amdgcn_mfma_f32_16x16x32_bf16(af, bfr, acc[ct], 0, 0, 0);
    }
  }
#undef PSTAGE

  // ---- K-split reduce: ks=1 dumps into its OWN (now idle) stage buffer ----
  if (ks == 1) {
#pragma unroll
    for (int ct = 0; ct < 4; ++ct)
      *(f32x4*)(wbuf + ct * 1024 + lane * 16) = acc[ct];
  }
  __syncthreads();
  if (ks == 0) {
    const char* pb = smem + (wave + 1) * 12288;   // partner's dump
#pragma unroll
    for (int ct = 0; ct < 4; ++ct) {
      f32x4 o = *(const f32x4*)(pb + ct * 1024 + lane * 16);
      int col = ct * 16 + rl;
      float bv = (col < 50) ? bias[col] : 0.f;
#pragma unroll
      for (int r = 0; r < 4; ++r) {
        int grow = row0 + q * 4 + r;               // D row = quad*4+reg (m89)
        float v = fmaxf(acc[ct][r] + o[r] + bv, 0.f);
        out[(long)grow * 64 + col] = (col < 50) ? v : 0.f;
      }
    }
  }
}

// MLP tail body: one block per batch row; sums the 23 per-job GEMM slices.
__device__ __forceinline__ void mix_body(
    int r, const float* __restrict__ pre,
    const float* __restrict__ b_gt, const float* __restrict__ b_gi,
    const float* __restrict__ W_m1, const float* __restrict__ b_m1,
    const float* __restrict__ W_m2, const float* __restrict__ b_m2,
    float* __restrict__ mix, float* smem) {
  float* sm = smem;            // [200]
  float* sh = smem + 200;      // [100]
  int t = threadIdx.x;
  if (t < 200) {
    float s1 = b_gt[t], s2 = b_gi[t];
#pragma unroll
    for (int j = 0; j < 7; ++j)  s1 += pre[(long)j * 25600 + r * 200 + t];
#pragma unroll
    for (int j = 7; j < 23; ++j) s2 += pre[(long)j * 25600 + r * 200 + t];
    sm[t] = fmaxf(s1, 0.f) + fmaxf(s2, 0.f);
  }
  __syncthreads();
  if (t < 100) {
    float a = b_m1[t];
#pragma unroll 4
    for (int k = 0; k < 200; ++k) a += sm[k] * W_m1[k * 100 + t];
    sh[t] = fmaxf(a, 0.f);
  }
  __syncthreads();
  if (t < 2) {
    float a = b_m2[t];
    for (int k = 0; k < 100; ++k) a += sh[k] * W_m2[k * 2 + t];
    mix[r * 2 + t] = a;
  }
}

// Grid order: img proj [0,144) first (longest: 32 steps/wave), txt proj
// [144,1168), mix [1168,1296) last (tiny).
__global__ __launch_bounds__(256)
void k_pm(
    const float* __restrict__ txt_region, const short* __restrict__ frt,
    const float* __restrict__ b_rt, float* __restrict__ tr,
    const float* __restrict__ img_region, const short* __restrict__ fri,
    const float* __restrict__ b_ri, float* __restrict__ ir,
    const float* __restrict__ pre,
    const float* __restrict__ b_gt, const float* __restrict__ b_gi,
    const float* __restrict__ W_m1, const float* __restrict__ b_m1,
    const float* __restrict__ W_m2, const float* __restrict__ b_m2,
    float* __restrict__ mix) {
  __shared__ __align__(16) char smem[49152];   // 4 waves x 12KB staging
  int bid = blockIdx.x;
  if (bid < 144)       proj_body<64>(img_region, fri, b_ri, ir, bid, smem);
  else if (bid < 1168) proj_body<24>(txt_region, frt, b_rt, tr, bid - 144, smem);
  else                 mix_body(bid - 1168, pre, b_gt, b_gi, W_m1, b_m1, W_m2, b_m2, mix, (float*)smem);
}

// ---------------------------------------------------------------------------
// Merged Sinkhorn kernel, MAX-PLUS. role 0: xx (n x n), role 1: xy (n x 36),
// role 2: yy (36 x 36).
// XX: C never leaves the CU -- stored as f16 in LDS CT[256][256] (128 KB,
// XOR-swizzled, aliases the dead Xf staging buffer), written straight from
// the MFMA accumulators. The 40-step max-plus loop runs on packed f16 via
// inline-asm v_pk_add_f16 / v_pk_max_f16 (ROCm 7.2 headers lack __hmax2
// device overloads) from conflict-free b128 LDS reads. This kills round-4's
// 1.3 GB of L2 remat reads and the 33 MB global Cxx round-trip.
// f16 is safe: |C*INV_EPS_LN2| < ~20K << 65504; Sinkhorn error damped by
// GAMMA=0.01 before the output.
// ---------------------------------------------------------------------------
#define SK_SMEM 139264

__global__ __launch_bounds__(1024)
void k_sink(
    const float* __restrict__ tr, const float* __restrict__ ir,
    const int* __restrict__ amask,
    float* __restrict__ Sxy, float* __restrict__ Sxx, float* __restrict__ Syy) {
  __shared__ __align__(16) char smem[SK_SMEM];
  int role = blockIdx.x >> 7;
  int b    = blockIdx.x & 127;
  int tid  = threadIdx.x;

  if (role == 0) {
    // ====================== XX ======================
    short*     Xf    = (short*)smem;              // 32 KB, dead after MFMA
    char*      CT    = smem;                      // f16 CT[256][512B], swizzled
    float*     norms = (float*)(smem + 131072);   // [256]
    float*     sPm   = (float*)(smem + 132096);   // [4][256]
    float*     sF    = (float*)(smem + 136192);   // [256]
    float*     sG    = (float*)(smem + 137216);   // [256]
    _Float16*  sAh   = (_Float16*)(smem + 138240);// [256]
    int*       nsh   = (int*)  (smem + 138784);
    if (tid < 64) {
      int c = 0;
      for (int i = tid; i < 256; i += 64) c += amask[b * 256 + i];
#pragma unroll
      for (int o = 1; o < 64; o <<= 1) c += __shfl_xor(c, o);
      if (tid == 0) *nsh = c;
    }
    const float* Xg = tr + (long)b * 256 * 64;
    for (int slot = tid; slot < 2048; slot += 1024) {
      int t = slot >> 7, k32 = (slot >> 6) & 1, l = slot & 63;
      int row = t * 16 + (l & 15), k0 = k32 * 32 + (l >> 4) * 8;
      const float* src = Xg + row * 64 + k0;
      f32x4 a0 = *(const f32x4*)src, a1 = *(const f32x4*)(src + 4);
      s16x8 p;
      p[0]=f2bf(a0[0]); p[1]=f2bf(a0[1]); p[2]=f2bf(a0[2]); p[3]=f2bf(a0[3]);
      p[4]=f2bf(a1[0]); p[5]=f2bf(a1[1]); p[6]=f2bf(a1[2]); p[7]=f2bf(a1[3]);
      *(s16x8*)(Xf + slot * 8) = p;
    }
    __syncthreads();
    int n = *nsh;
    // G = X X^T via MFMA. wave wv owns 16-row strip.
    int wv = tid >> 6, lane = tid & 63, q = lane >> 4;
    f32x4 acc[16];
#pragma unroll
    for (int ct = 0; ct < 16; ++ct) acc[ct] = (f32x4){0.f, 0.f, 0.f, 0.f};
    s16x8 afr0 = *(const s16x8*)(Xf + ((wv * 2 + 0) * 64 + lane) * 8);
    s16x8 afr1 = *(const s16x8*)(Xf + ((wv * 2 + 1) * 64 + lane) * 8);
#pragma unroll
    for (int ct = 0; ct < 16; ++ct) {
      s16x8 b0 = *(const s16x8*)(Xf + ((ct * 2 + 0) * 64 + lane) * 8);
      s16x8 b1 = *(const s16x8*)(Xf + ((ct * 2 + 1) * 64 + lane) * 8);
      acc[ct] = __builtin_amdgcn_mfma_f32_16x16x32_bf16(afr0, b0, acc[ct], 0, 0, 0);
      acc[ct] = __builtin_amdgcn_mfma_f32_16x16x32_bf16(afr1, b1, acc[ct], 0, 0, 0);
    }
#pragma unroll
    for (int r = 0; r < 4; ++r) {                 // diag of tile (wv,wv) = ||x||^2
      int m_ = q * 4 + r;
      if ((lane & 15) == m_) norms[wv * 16 + m_] = acc[wv][r];
    }
    __syncthreads();                              // MFMA reads of Xf done
    // ---- write CT (f16, swizzled): CT[j][i] = D_ij, byte ^= (j&7)<<4 ----
    int i0w = wv * 16 + q * 4;
    float ni0 = norms[i0w], ni1 = norms[i0w + 1];
    float ni2 = norms[i0w + 2], ni3 = norms[i0w + 3];
#pragma unroll
    for (int ct = 0; ct < 16; ++ct) {
      int j = ct * 16 + (lane & 15);
      float nj = norms[j];
      float v0 = (acc[ct][0] - 0.5f * (ni0 + nj)) * INV_EPS_LN2;
      float v1 = (acc[ct][1] - 0.5f * (ni1 + nj)) * INV_EPS_LN2;
      float v2 = (acc[ct][2] - 0.5f * (ni2 + nj)) * INV_EPS_LN2;
      float v3 = (acc[ct][3] - 0.5f * (ni3 + nj)) * INV_EPS_LN2;
      char* p = CT + (((j << 9) + (i0w << 1)) ^ ((j & 7) << 4));
      unsigned p01 = (unsigned)f2h(v0) | ((unsigned)f2h(v1) << 16);
      unsigned p23 = (unsigned)f2h(v2) | ((unsigned)f2h(v3) << 16);
      *(unsigned*)(p)     = p01;
      *(unsigned*)(p + 4) = p23;
    }
    float log2n = log2f((float)n);
    if (tid < 256) {
      sF[tid] = 0.f;
      sAh[tid] = (tid < n) ? (_Float16)(-log2n) : (_Float16)(-65504.f);
    }
    __syncthreads();
    // ---- 40 max-plus half-steps, packed f16 (inline asm pk ops) ----
    int kk = tid >> 8, j = tid & 255, i0 = kk * 64;
    unsigned base = (unsigned)((j << 9) + (i0 << 1));
    unsigned sw   = (unsigned)((j & 7) << 4);
    const unsigned* ah2 = (const unsigned*)(sAh) + kk * 32;
    for (int h = 0; h < 40; ++h) {
      unsigned mm = 0xFBFFFBFFu;                  // {-65504, -65504}
#pragma unroll
      for (int s = 0; s < 8; ++s) {
        u32x4 v = *(const u32x4*)(CT + ((base + (s << 4)) ^ sw));
        unsigned a0 = ah2[s * 4 + 0], a1 = ah2[s * 4 + 1];
        unsigned a2 = ah2[s * 4 + 2], a3 = ah2[s * 4 + 3];
        unsigned t0, t1, t2, t3;
        asm("v_pk_add_f16 %0, %1, %2" : "=v"(t0) : "v"(v[0]), "v"(a0));
        asm("v_pk_add_f16 %0, %1, %2" : "=v"(t1) : "v"(v[1]), "v"(a1));
        asm("v_pk_add_f16 %0, %1, %2" : "=v"(t2) : "v"(v[2]), "v"(a2));
        asm("v_pk_add_f16 %0, %1, %2" : "=v"(t3) : "v"(v[3]), "v"(a3));
        asm("v_pk_max_f16 %0, %0, %1" : "+v"(mm) : "v"(t0));
        asm("v_pk_max_f16 %0, %0, %1" : "+v"(mm) : "v"(t1));
        asm("v_pk_max_f16 %0, %0, %1" : "+v"(mm) : "v"(t2));
        asm("v_pk_max_f16 %0, %0, %1" : "+v"(mm) : "v"(t3));
      }
      sPm[kk * 256 + j] = fmaxf(h2f((unsigned short)(mm & 0xFFFFu)),
                                h2f((unsigned short)(mm >> 16)));
      __syncthreads();
      if (tid < 256) {
        float m4 = fmaxf(fmaxf(sPm[tid], sPm[256 + tid]),
                         fmaxf(sPm[512 + tid], sPm[768 + tid]));
        if (tid < n) {
          ((h & 1) ? sF : sG)[tid] = -EPS_LN2 * m4;
          sAh[tid] = (_Float16)(-log2n - m4);
        }
      }
      __syncthreads();
    }
    if (tid < 64) {
      float a = 0.f;
      for (int i = tid; i < n; i += 64) a += sF[i] + sG[i];
#pragma unroll
      for (int o = 1; o < 64; o <<= 1) a += __shfl_xor(a, o);
      if (tid == 0) Sxx[b] = a / n;
    }
  } else if (role == 1) {
    // ====================== XY ======================
    float* Ys  = (float*)smem;                    // [36][64]
    float* Cs  = (float*)(smem + 9216);           // [256][37]
    float* nx  = (float*)(smem + 47104);          // [256]
    float* ny  = (float*)(smem + 48128);          // [36]
    float* sA  = (float*)(smem + 48288);          // padded alpha [272]
    float* sB  = (float*)(smem + 49376);          // beta [36]
    float* sF  = (float*)(smem + 49536);          // [256]
    float* sG  = (float*)(smem + 50560);          // [36]
    int*   nsh = (int*)  (smem + 50720);
    if (tid < 64) {
      int c = 0;
      for (int i = tid; i < 256; i += 64) c += amask[b * 256 + i];
#pragma unroll
      for (int o = 1; o < 64; o <<= 1) c += __shfl_xor(c, o);
      if (tid == 0) *nsh = c;
    }
    const float* Xg = tr + (long)b * 256 * 64;
    const float* Yg = ir + (long)b * 36 * 64;
    for (int idx = tid; idx < 576; idx += 1024) {
      int row = idx >> 4, q4 = idx & 15;
      *(f32x4*)(Ys + row * 64 + q4 * 4) = *(const f32x4*)(Yg + row * 64 + q4 * 4);
    }
    __syncthreads();
    int n = *nsh;
    if (tid < 256) {
      float a = 0.f;
#pragma unroll
      for (int q4 = 0; q4 < 13; ++q4) {
        f32x4 v = *(const f32x4*)(Xg + tid * 64 + q4 * 4);
        a += v[0]*v[0] + v[1]*v[1] + v[2]*v[2] + v[3]*v[3];
      }
      nx[tid] = a;
    } else if (tid < 292) {
      int jj = tid - 256; float a = 0.f;
#pragma unroll
      for (int q4 = 0; q4 < 13; ++q4) {
        f32x4 v = *(const f32x4*)(Ys + jj * 64 + q4 * 4);
        a += v[0]*v[0] + v[1]*v[1] + v[2]*v[2] + v[3]*v[3];
      }
      ny[jj] = a;
    }
    __syncthreads();
    if (tid < 1008) {
      int ii = tid / 36, jj = tid - ii * 36;
      f32x4 yr[13];
#pragma unroll
      for (int q4 = 0; q4 < 13; ++q4) yr[q4] = *(const f32x4*)(Ys + jj * 64 + q4 * 4);
      float nyj = ny[jj];
      for (int i = ii; i < 256; i += 28) {
        float d = 0.f;
#pragma unroll
        for (int q4 = 0; q4 < 13; ++q4) {
          f32x4 xv = *(const f32x4*)(Xg + i * 64 + q4 * 4);
          d += xv[0]*yr[q4][0] + xv[1]*yr[q4][1] + xv[2]*yr[q4][2] + xv[3]*yr[q4][3];
        }
        Cs[i * 37 + jj] = (d - 0.5f * (nx[i] + nyj)) * INV_EPS_LN2;
      }
    }
    __syncthreads();
    int jg = tid >> 4, kg = tid & 15;             // g-role: column jg, slice kg
    float Cg[16];
    if (jg < 36) {
#pragma unroll
      for (int t = 0; t < 16; ++t) Cg[t] = Cs[(kg * 16 + t) * 37 + jg];
    }
    int fi = tid >> 2, kf = tid & 3;              // f-role: row fi, slice kf
    float Cf[9];
#pragma unroll
    for (int t = 0; t < 9; ++t) {
      int jj2 = kf * 9 + t;
      Cf[t] = (jj2 < 36) ? Cs[fi * 37 + jj2] : 0.f;
    }
    float log2n = log2f((float)n);
    if (tid < 256) { sF[tid] = 0.f; sA[tid + (tid >> 4)] = -log2n; }
    __syncthreads();
    const float* agp = sA + kg * 17;
    int gend = n - kg * 16; if (gend > 16) gend = 16;
    for (int it = 0; it < 20; ++it) {
      float gm = -1e30f;
      if (jg < 36) {
#pragma unroll
        for (int t = 0; t < 16; ++t)
          if (t < gend) gm = fmaxf(gm, agp[t] + Cg[t]);
        gm = fmaxf(gm, __shfl_xor(gm, 1)); gm = fmaxf(gm, __shfl_xor(gm, 2));
        gm = fmaxf(gm, __shfl_xor(gm, 4)); gm = fmaxf(gm, __shfl_xor(gm, 8));
      }
      __syncthreads();
      if (jg < 36 && kg == 0) {
        sG[jg] = -EPS_LN2 * gm;
        sB[jg] = -LOG2_36 - gm;
      }
      __syncthreads();
      float fm = -1e30f;
#pragma unroll
      for (int t = 0; t < 9; ++t) {
        int jj2 = kf * 9 + t;
        if (jj2 < 36) fm = fmaxf(fm, sB[jj2] + Cf[t]);
      }
      fm = fmaxf(fm, __shfl_xor(fm, 1)); fm = fmaxf(fm, __shfl_xor(fm, 2));
      __syncthreads();
      if (kf == 0 && fi < n) {
        sF[fi] = -EPS_LN2 * fm;
        sA[fi + (fi >> 4)] = -log2n - fm;
      }
      __syncthreads();
    }
    if (tid < 64) {
      float a = 0.f;
      for (int i = tid; i < n; i += 64) a += sF[i];
      float g = (tid < 36) ? sG[tid] : 0.f;
#pragma unroll
      for (int o = 1; o < 64; o <<= 1) { a += __shfl_xor(a, o); g += __shfl_xor(g, o); }
      if (tid == 0) Sxy[b] = a / n + g / 36.f;
    }
  } else {
    // ====================== YY ======================
    float* Ys = (float*)smem;                     // [36][64]
    float* Cs = (float*)(smem + 9216);            // [36][37]
    float* ny = (float*)(smem + 48128);
    float* sA = (float*)(smem + 48288);           // [36]
    float* sF = (float*)(smem + 49536);
    float* sG = (float*)(smem + 50560);
    const float* Yg = ir + (long)b * 36 * 64;
    for (int idx = tid; idx < 576; idx += 1024) {
      int row = idx >> 4, q4 = idx & 15;
      *(f32x4*)(Ys + row * 64 + q4 * 4) = *(const f32x4*)(Yg + row * 64 + q4 * 4);
    }
    __syncthreads();
    if (tid < 36) {
      float a = 0.f;
#pragma unroll
      for (int q4 = 0; q4 < 13; ++q4) {
        f32x4 v = *(const f32x4*)(Ys + tid * 64 + q4 * 4);
        a += v[0]*v[0] + v[1]*v[1] + v[2]*v[2] + v[3]*v[3];
      }
      ny[tid] = a;
    }
    __syncthreads();
    if (tid < 1008) {
      int ii = tid / 36, jj = tid - ii * 36;
      f32x4 yr[13];
#pragma unroll
      for (int q4 = 0; q4 < 13; ++q4) yr[q4] = *(const f32x4*)(Ys + jj * 64 + q4 * 4);
      float nyj = ny[jj];
      for (int i = ii; i < 36; i += 28) {
        float d = 0.f;
#pragma unroll
        for (int q4 = 0; q4 < 13; ++q4) {
          f32x4 xv = *(const f32x4*)(Ys + i * 64 + q4 * 4);
          d += xv[0]*yr[q4][0] + xv[1]*yr[q4][1] + xv[2]*yr[q4][2] + xv[3]*yr[q4][3];
        }
        Cs[i * 37 + jj] = (d - 0.5f * (ny[i] + nyj)) * INV_EPS_LN2;
      }
    }
    __syncthreads();
    int j = tid >> 2, kk = tid & 3;
    float Creg[9];
    if (j < 36) {
#pragma unroll
      for (int t = 0; t < 9; ++t) {
        int i2 = kk * 9 + t;
        Creg[t] = (i2 < 36) ? Cs[i2 * 37 + j] : 0.f;
      }
    }
    if (tid < 36) { sF[tid] = 0.f; sA[tid] = -LOG2_36; }
    __syncthreads();
    for (int h = 0; h < 40; ++h) {
      float m = -1e30f;
      if (j < 36) {
#pragma unroll
        for (int t = 0; t < 9; ++t) {
          int i2 = kk * 9 + t;
          if (i2 < 36) m = fmaxf(m, sA[i2] + Creg[t]);
        }
        m = fmaxf(m, __shfl_xor(m, 1)); m = fmaxf(m, __shfl_xor(m, 2));
      }
      __syncthreads();
      if (j < 36 && kk == 0) {
        ((h & 1) ? sF : sG)[j] = -EPS_LN2 * m;
        sA[j] = -LOG2_36 - m;
      }
      __syncthreads();
    }
    if (tid < 64) {
      float a = (tid < 36) ? sF[tid] + sG[tid] : 0.f;
#pragma unroll
      for (int o = 1; o < 64; o <<= 1) a += __shfl_xor(a, o);
      if (tid == 0) Syy[b] = a / 36.f;
    }
  }
}

// ---------------------------------------------------------------------------
// Final combine: w_dis -> w_pred, max with mix_pred, 2-way softmax.
// ---------------------------------------------------------------------------
__global__ void k_final(const float* __restrict__ mix, const float* __restrict__ sxy,
                        const float* __restrict__ sxx, const float* __restrict__ syy,
                        float* __restrict__ out) {
  int b = blockIdx.x * 64 + threadIdx.x;
  if (b < 128) {
    float w  = sxy[b] - 0.5f * (sxx[b] + syy[b]);
    float x0 = fmaxf(mix[b * 2 + 0], 1.0f - 0.01f * w);
    float x1 = fmaxf(mix[b * 2 + 1], 0.01f * w);
    float mx = fmaxf(x0, x1);
    float e0 = expf(x0 - mx), e1 = expf(x1 - mx);
    float inv = 1.f / (e0 + e1);
    out[b * 2 + 0] = e0 * inv;
    out[b * 2 + 1] = e1 * inv;
  }
}

// ---------------------------------------------------------------------------
extern "C" void kernel_launch(void* const* d_in, const int* in_sizes, int n_in,
                              void* d_out, int out_size, void* d_ws, size_t ws_size,
                              hipStream_t stream) {
  const float* txt_global = (const float*)d_in[0];
  const float* txt_region = (const float*)d_in[1];
  const float* img_global = (const float*)d_in[2];
  const float* img_region = (const float*)d_in[3];
  const float* social     = (const float*)d_in[4];
  const int*   attn_mask  = (const int*)  d_in[5];
  const float* W_stat = (const float*)d_in[6];  const float* b_stat = (const float*)d_in[7];
  const float* W_gt   = (const float*)d_in[8];  const float* b_gt   = (const float*)d_in[9];
  const float* W_gi   = (const float*)d_in[10]; const float* b_gi   = (const float*)d_in[11];
  const float* W_rt   = (const float*)d_in[12]; const float* b_rt   = (const float*)d_in[13];
  const float* W_ri   = (const float*)d_in[14]; const float* b_ri   = (const float*)d_in[15];
  const float* W_m1   = (const float*)d_in[16]; const float* b_m1   = (const float*)d_in[17];
  const float* W_m2   = (const float*)d_in[18]; const float* b_m2   = (const float*)d_in[19];

  float* ws = (float*)d_ws;
  float* ws_mix = ws;                    // 256
  float* ws_sxy = ws + 256;              // 128
  float* ws_sxx = ws + 384;              // 128
  float* ws_syy = ws + 512;              // 128
  short* ws_frt = (short*)(ws + 1024);   // 49152 shorts -> ends float 25600
  short* ws_fri = (short*)(ws + 25600);  // 131072 shorts -> ends float 91136
  float* ws_tr  = ws + 131072;           // [32768][64]
  float* ws_ir  = ws + 2228224;          // [4608][64]
  float* ws_pre = ws + 2523136;          // [23][128][200]

  k_prep<<<456, 256, 0, stream>>>(W_rt, W_ri, ws_frt, ws_fri,
                                  txt_global, img_global, social,
                                  W_stat, b_stat, W_gt, W_gi, ws_pre);
  k_pm<<<1296, 256, 0, stream>>>(txt_region, ws_frt, b_rt, ws_tr,
                                 img_region, ws_fri, b_ri, ws_ir,
                                 ws_pre, b_gt, b_gi,
                                 W_m1, b_m1, W_m2, b_m2, ws_mix);
  k_sink<<<384, 1024, 0, stream>>>(ws_tr, ws_ir, attn_mask,
                                   ws_sxy, ws_sxx, ws_syy);
  k_final<<<2, 64, 0, stream>>>(ws_mix, ws_sxy, ws_sxx, ws_syy, (float*)d_out);
}